// Round 8
// baseline (249.390 us; speedup 1.0000x reference)
//
#include <hip/hip_runtime.h>
#include <hip/hip_fp16.h>

// ---------------------------------------------------------------------------
// GAT 2-layer forward. N=50000 nodes, F=128, E=1.6M random edges (+N implicit
// self loops). L1: H=2,C=64 concat -> relu. L2: H=1,C=16.
//
// CSR build (atomic-minimized; measured: each device-scope atomicAdd costs a
// ~64B HBM write -> minimize COUNT, not locality). Buckets have fixed
// CAPACITY SLACK segments (no global scan): prep (w1 transpose + cursor
// init) -> partition (per-block LDS hist + bulk reservation + packed
// scatter) -> bucket_build (all-LDS degree/scan/scatter; nodeseg=int2).
//
// agg1 fuses: softmax-weighted aggregation + relu + bias (h in registers
// only) + gemm2 (h @ w2^T, w2 L1-resident) + layer-2 logits.
// Row-split gathers with deep MLP: agg1 4 rows x 16 lanes x 16B, 16-edge
// unroll -> 4 uint4 gathers in flight; agg2 8 rows x 8 lanes x 4B, 16-edge
// unroll -> 2 loads in flight. LDS stages byte offsets (s<<8 / s<<5) to
// avoid per-load 64-bit muls.
// Softmax without max-shift (logits bounded, fp32 exp safe; ratio identical
// to reference in exact math). xw stored fp16 (2^-11 rel err).
// ---------------------------------------------------------------------------

#define BSHIFT 7                 // 128 dst nodes per bucket
#define MAXB 512                 // supports N <= 65536

__device__ __forceinline__ float lrelu(float a) { return fmaxf(a, 0.2f * a); }

// ---------------- prep: w1 transpose + bucket cursor init ----------------

__global__ __launch_bounds__(256) void prep_kernel(const float* __restrict__ w1,
                                                   float* __restrict__ w1T,
                                                   int* __restrict__ bincur,
                                                   int B, int CAP) {
  int idx = blockIdx.x * 256 + threadIdx.x;  // grid 64 -> 16384
  int o = idx >> 7, i = idx & 127;
  w1T[i * 128 + o] = w1[idx];
  if (idx < B) bincur[idx] = idx * CAP;
}

// ---------------- CSR build ----------------

// partition edges into fixed-capacity bucket segments; packed 4B entries.
__global__ __launch_bounds__(256) void partition_kernel(const int* __restrict__ src,
                                                        const int* __restrict__ dst,
                                                        int* __restrict__ bincur,
                                                        unsigned* __restrict__ binned,
                                                        int E, int B, int CH) {
  __shared__ int s_h[MAXB];
  __shared__ int s_base[MAXB];
  __shared__ int s_cur[MAXB];
  for (int i = threadIdx.x; i < B; i += 256) s_h[i] = 0;
  __syncthreads();
  int lo = blockIdx.x * CH, hi = min(lo + CH, E);
  for (int e = lo + threadIdx.x; e < hi; e += 256)
    atomicAdd(&s_h[dst[e] >> BSHIFT], 1);
  __syncthreads();
  for (int i = threadIdx.x; i < B; i += 256) {
    int c = s_h[i];
    s_base[i] = c ? atomicAdd(&bincur[i], c) : 0;  // one bulk reservation
    s_cur[i] = 0;
  }
  __syncthreads();
  for (int e = lo + threadIdx.x; e < hi; e += 256) {
    int d = dst[e];
    int b = d >> BSHIFT;
    int r = atomicAdd(&s_cur[b], 1);
    binned[s_base[b] + r] = (unsigned)src[e] | ((unsigned)(d & 127) << 16);
  }
}

// one block per bucket: local degree/scan/scatter entirely in LDS.
// Bucket b's data: [b*CAP, bincur[b]). Writes nodeseg + csr (gaps ok).
__global__ __launch_bounds__(256) void bucket_build_kernel(const unsigned* __restrict__ binned,
                                                           const int* __restrict__ bincur,
                                                           int2* __restrict__ nodeseg,
                                                           int* __restrict__ csr,
                                                           int N, int CAP) {
  __shared__ int s_deg[128];
  __shared__ int s_cur[128];
  __shared__ int s_wsum;
  int b = blockIdx.x;
  int lo = b * CAP, hi = bincur[b];
  int t = threadIdx.x;
  if (t < 128) s_deg[t] = 0;
  __syncthreads();
  for (int i = lo + t; i < hi; i += 256)
    atomicAdd(&s_deg[binned[i] >> 16], 1);
  __syncthreads();
  int lane = t & 63, wv = t >> 6;
  int v = (t < 128) ? s_deg[t] : 0;
  int incl = v;
#pragma unroll
  for (int off = 1; off < 64; off <<= 1) {
    int u = __shfl_up(incl, off);
    if (lane >= off) incl += u;
  }
  if (t == 63) s_wsum = incl;  // wave-0 total
  __syncthreads();
  int excl = incl - v + ((wv == 1) ? s_wsum : 0);
  if (t < 128) {
    int node = (b << BSHIFT) + t;
    if (node < N) nodeseg[node] = make_int2(lo + excl, lo + excl + v);
    s_cur[t] = lo + excl;
  }
  __syncthreads();
  for (int i = lo + t; i < hi; i += 256) {
    unsigned e = binned[i];
    int p = atomicAdd(&s_cur[e >> 16], 1);  // LDS atomic
    csr[p] = (int)(e & 0xFFFFu);
  }
}

// ---------------- layer 1 dense + fused logits ----------------

// 32-node tile, 256 threads. LDS 18.4KB. xw1h fp16 [n][o]; logits fused.
__global__ __launch_bounds__(256) void gemm1_kernel(const float* __restrict__ x,
                                                    const float* __restrict__ w1T,
                                                    const float* __restrict__ as1,
                                                    const float* __restrict__ ad1,
                                                    __half* __restrict__ xw1h,
                                                    float* __restrict__ asrc1,
                                                    float* __restrict__ adst1, int N) {
  __shared__ __align__(16) float xT[128 * 36];  // [i][node], stride 36 (pad)
  int t = threadIdx.x;
  int n0 = blockIdx.x * 32;
#pragma unroll
  for (int k = 0; k < 4; ++k) {
    int nd = 8 * k + (t >> 5);
    int i = 4 * (t & 31);
    int gn = n0 + nd;
    float4 v = (gn < N) ? *(const float4*)&x[(size_t)gn * 128 + i]
                        : make_float4(0.f, 0.f, 0.f, 0.f);
    xT[(i + 0) * 36 + nd] = v.x;
    xT[(i + 1) * 36 + nd] = v.y;
    xT[(i + 2) * 36 + nd] = v.z;
    xT[(i + 3) * 36 + nd] = v.w;
  }
  __syncthreads();
  int cg = t & 31, ng = t >> 5;
  int o0 = cg * 4, nlo = ng * 4;
  float acc[4][4];
#pragma unroll
  for (int a = 0; a < 4; ++a)
#pragma unroll
    for (int b = 0; b < 4; ++b) acc[a][b] = 0.f;

#pragma unroll 8
  for (int i = 0; i < 128; ++i) {
    float4 xv = *(const float4*)&xT[i * 36 + nlo];
    float4 wv = *(const float4*)&w1T[i * 128 + o0];
    float xs[4] = {xv.x, xv.y, xv.z, xv.w};
    float ws[4] = {wv.x, wv.y, wv.z, wv.w};
#pragma unroll
    for (int a = 0; a < 4; ++a)
#pragma unroll
      for (int b = 0; b < 4; ++b) acc[a][b] += xs[a] * ws[b];
  }

  float asv[4], adv[4];
#pragma unroll
  for (int b = 0; b < 4; ++b) {
    asv[b] = as1[o0 + b];
    adv[b] = ad1[o0 + b];
  }

#pragma unroll
  for (int a = 0; a < 4; ++a) {
    int n = n0 + nlo + a;
    bool ok = (n < N);
    float ps = 0.f, pd = 0.f;
#pragma unroll
    for (int b = 0; b < 4; ++b) {
      ps += acc[a][b] * asv[b];
      pd += acc[a][b] * adv[b];
    }
#pragma unroll
    for (int k = 1; k < 16; k <<= 1) {
      ps += __shfl_xor(ps, k);
      pd += __shfl_xor(pd, k);
    }
    if (ok && (cg & 15) == 0) {
      int hh = cg >> 4;
      asrc1[2 * n + hh] = ps;
      adst1[2 * n + hh] = pd;
    }
    if (ok) {
      union {
        __half h[4];
        uint2 u;
      } pk;
#pragma unroll
      for (int b = 0; b < 4; ++b) pk.h[b] = __float2half(acc[a][b]);
      *(uint2*)&xw1h[(size_t)n * 128 + o0] = pk.u;
    }
  }
}

// wave per dst node. 4 rows x 16 lanes x 16B; 16-edge unroll = 4 uint4
// gathers in flight. Epilogue fuses relu+bias+gemm2+layer-2 logits.
__global__ __launch_bounds__(256) void agg1_kernel(const __half* __restrict__ xw1h,
                                                   const float* __restrict__ asrc1,
                                                   const float* __restrict__ adst1,
                                                   const float* __restrict__ b1,
                                                   const float* __restrict__ w2,
                                                   const float* __restrict__ as2,
                                                   const float* __restrict__ ad2,
                                                   const int* __restrict__ csr,
                                                   const int2* __restrict__ nodeseg,
                                                   __half* __restrict__ xw2h,
                                                   float* __restrict__ asrc2,
                                                   float* __restrict__ adst2, int N) {
  __shared__ int s_off[4][64];      // row byte offset (s * 256)
  __shared__ float2 s_w[4][64];     // exp weights per head
  int lane = threadIdx.x & 63, wv = threadIdx.x >> 6;
  int d = blockIdx.x * 4 + wv;
  if (d >= N) return;
  int c8 = lane & 15;   // channels 8*c8 .. 8*c8+7
  int row = lane >> 4;  // 0..3 edge subgroup
  int head = c8 >> 3;   // head of these channels
  int2 seg = nodeseg[d];
  int e0 = seg.x, e1 = seg.y;
  float2 asv = *(const float2*)&asrc1[2 * d];
  float2 adv = *(const float2*)&adst1[2 * d];
  float wself = __expf(lrelu(head ? (asv.y + adv.y) : (asv.x + adv.x)));

  const char* xb = (const char*)xw1h + 16 * c8;  // channel base

  float a[8];
  float sum = 0.f;
#pragma unroll
  for (int k = 0; k < 8; ++k) a[k] = 0.f;
  if (row == 0) {  // self edge handled once, by row 0
    uint4 r = *(const uint4*)(xb + ((size_t)d << 8));
    const __half2* hp = (const __half2*)&r;
#pragma unroll
    for (int k = 0; k < 4; ++k) {
      float2 v = __half22float2(hp[k]);
      a[2 * k] = wself * v.x;
      a[2 * k + 1] = wself * v.y;
    }
    sum = wself;
  }

  for (int base = e0; base < e1; base += 64) {
    int cnt = min(64, e1 - base);
    if (lane < cnt) {
      int s = csr[base + lane];
      float2 aa = *(const float2*)&asrc1[2 * s];
      s_off[wv][lane] = s << 8;
      float2 w;
      w.x = __expf(lrelu(aa.x + adv.x));
      w.y = __expf(lrelu(aa.y + adv.y));
      s_w[wv][lane] = w;
    }
    // wave-private LDS: same wave wrote it; no barrier needed
    int j = 0;
    for (; j + 15 < cnt; j += 16) {
      int o0 = s_off[wv][j + row];
      int o1 = s_off[wv][j + 4 + row];
      int o2 = s_off[wv][j + 8 + row];
      int o3 = s_off[wv][j + 12 + row];
      float w0 = ((const float*)&s_w[wv][j + row])[head];
      float w1 = ((const float*)&s_w[wv][j + 4 + row])[head];
      float w2v = ((const float*)&s_w[wv][j + 8 + row])[head];
      float w3 = ((const float*)&s_w[wv][j + 12 + row])[head];
      uint4 r0 = *(const uint4*)(xb + o0);
      uint4 r1 = *(const uint4*)(xb + o1);
      uint4 r2 = *(const uint4*)(xb + o2);
      uint4 r3 = *(const uint4*)(xb + o3);
      const __half2* h0 = (const __half2*)&r0;
      const __half2* h1 = (const __half2*)&r1;
      const __half2* h2 = (const __half2*)&r2;
      const __half2* h3 = (const __half2*)&r3;
#pragma unroll
      for (int k = 0; k < 4; ++k) {
        float2 v0 = __half22float2(h0[k]);
        float2 v1 = __half22float2(h1[k]);
        float2 v2 = __half22float2(h2[k]);
        float2 v3 = __half22float2(h3[k]);
        a[2 * k] += w0 * v0.x + w1 * v1.x + w2v * v2.x + w3 * v3.x;
        a[2 * k + 1] += w0 * v0.y + w1 * v1.y + w2v * v2.y + w3 * v3.y;
      }
      sum += w0 + w1 + w2v + w3;
    }
    for (; j < cnt; j += 4) {
      if (row < cnt - j) {
        int oA = s_off[wv][j + row];
        float wA = ((const float*)&s_w[wv][j + row])[head];
        uint4 rA = *(const uint4*)(xb + oA);
        const __half2* hA = (const __half2*)&rA;
#pragma unroll
        for (int k = 0; k < 4; ++k) {
          float2 vA = __half22float2(hA[k]);
          a[2 * k] += wA * vA.x;
          a[2 * k + 1] += wA * vA.y;
        }
        sum += wA;
      }
    }
  }

  // butterfly across the 4 rows -> every lane holds full sums for its c8
#pragma unroll
  for (int k = 0; k < 8; ++k) {
    a[k] += __shfl_xor(a[k], 16);
    a[k] += __shfl_xor(a[k], 32);
  }
  sum += __shfl_xor(sum, 16);
  sum += __shfl_xor(sum, 32);

  // h (relu'd, biased) in registers — every lane holds 8 channels
  float inv = 1.f / (sum + 1e-16f);
  float4 blo = *(const float4*)&b1[8 * c8];
  float4 bhi = *(const float4*)&b1[8 * c8 + 4];
  float h[8];
  h[0] = fmaxf(a[0] * inv + blo.x, 0.f);
  h[1] = fmaxf(a[1] * inv + blo.y, 0.f);
  h[2] = fmaxf(a[2] * inv + blo.z, 0.f);
  h[3] = fmaxf(a[3] * inv + blo.w, 0.f);
  h[4] = fmaxf(a[4] * inv + bhi.x, 0.f);
  h[5] = fmaxf(a[5] * inv + bhi.y, 0.f);
  h[6] = fmaxf(a[6] * inv + bhi.z, 0.f);
  h[7] = fmaxf(a[7] * inv + bhi.w, 0.f);

  // fused gemm2: row r computes xw2 channels r*4..r*4+3 (butterfly over 16)
  float p[4];
#pragma unroll
  for (int cc = 0; cc < 4; ++cc) {
    const float4 wlo = *(const float4*)&w2[(row * 4 + cc) * 128 + 8 * c8];
    const float4 whi = *(const float4*)&w2[(row * 4 + cc) * 128 + 8 * c8 + 4];
    p[cc] = h[0] * wlo.x + h[1] * wlo.y + h[2] * wlo.z + h[3] * wlo.w +
            h[4] * whi.x + h[5] * whi.y + h[6] * whi.z + h[7] * whi.w;
#pragma unroll
    for (int k = 1; k < 16; k <<= 1) p[cc] += __shfl_xor(p[cc], k);
  }
  float qs = 0.f, qd = 0.f;
#pragma unroll
  for (int cc = 0; cc < 4; ++cc) {
    qs += p[cc] * as2[row * 4 + cc];
    qd += p[cc] * ad2[row * 4 + cc];
  }
  qs += __shfl_xor(qs, 16);
  qs += __shfl_xor(qs, 32);
  qd += __shfl_xor(qd, 16);
  qd += __shfl_xor(qd, 32);
  if (lane == 0) {
    asrc2[d] = qs;
    adst2[d] = qd;
  }
  if (c8 == 0) {  // one lane per row stores its 4 channels (8B)
    union {
      __half hh[4];
      uint2 u;
    } pk;
#pragma unroll
    for (int cc = 0; cc < 4; ++cc) pk.hh[cc] = __float2half(p[cc]);
    *(uint2*)&xw2h[(size_t)d * 16 + row * 4] = pk.u;
  }
}

// wave per dst node. 8 rows x 8 lanes x 4B; 16-edge unroll = 2 loads in
// flight. Each lane owns 2 channels (half2).
__global__ __launch_bounds__(256) void agg2_kernel(const __half* __restrict__ xw2h,
                                                   const float* __restrict__ asrc2,
                                                   const float* __restrict__ adst2,
                                                   const float* __restrict__ b2,
                                                   const int* __restrict__ csr,
                                                   const int2* __restrict__ nodeseg,
                                                   float* __restrict__ out, int N) {
  __shared__ int s_off[4][64];   // row byte offset (s * 32)
  __shared__ float s_w[4][64];
  int lane = threadIdx.x & 63, wv = threadIdx.x >> 6;
  int d = blockIdx.x * 4 + wv;
  if (d >= N) return;
  int c2 = lane & 7;   // channels 2*c2, 2*c2+1
  int row = lane >> 3; // 0..7
  int2 seg = nodeseg[d];
  int e0 = seg.x, e1 = seg.y;
  float advd = adst2[d];
  float wself = __expf(lrelu(asrc2[d] + advd));
  const char* xb = (const char*)xw2h + 4 * c2;

  float a0 = 0.f, a1 = 0.f, sum = 0.f;
  if (row == 0) {
    float2 v = __half22float2(*(const __half2*)(xb + (size_t)d * 32));
    a0 = wself * v.x;
    a1 = wself * v.y;
    sum = wself;
  }
  for (int base = e0; base < e1; base += 64) {
    int cnt = min(64, e1 - base);
    if (lane < cnt) {
      int s = csr[base + lane];
      s_off[wv][lane] = s << 5;
      s_w[wv][lane] = __expf(lrelu(asrc2[s] + advd));
    }
    int j = 0;
    for (; j + 15 < cnt; j += 16) {
      int o0 = s_off[wv][j + row];
      int o1 = s_off[wv][j + 8 + row];
      float w0 = s_w[wv][j + row];
      float w1 = s_w[wv][j + 8 + row];
      float2 v0 = __half22float2(*(const __half2*)(xb + o0));
      float2 v1 = __half22float2(*(const __half2*)(xb + o1));
      a0 += w0 * v0.x + w1 * v1.x;
      a1 += w0 * v0.y + w1 * v1.y;
      sum += w0 + w1;
    }
    for (; j + 7 < cnt; j += 8) {
      int o0 = s_off[wv][j + row];
      float w0 = s_w[wv][j + row];
      float2 v0 = __half22float2(*(const __half2*)(xb + o0));
      a0 += w0 * v0.x;
      a1 += w0 * v0.y;
      sum += w0;
    }
    if (row < cnt - j) {  // tail: rows 0..cnt-j-1 take one edge each
      int o0 = s_off[wv][j + row];
      float w0 = s_w[wv][j + row];
      float2 v0 = __half22float2(*(const __half2*)(xb + o0));
      a0 += w0 * v0.x;
      a1 += w0 * v0.y;
      sum += w0;
    }
  }
#pragma unroll
  for (int k = 8; k < 64; k <<= 1) {
    a0 += __shfl_xor(a0, k);
    a1 += __shfl_xor(a1, k);
    sum += __shfl_xor(sum, k);
  }
  if (lane < 8) {
    float inv = 1.f / (sum + 1e-16f);
    float2 r;
    r.x = a0 * inv + b2[2 * c2];
    r.y = a1 * inv + b2[2 * c2 + 1];
    *(float2*)&out[(size_t)d * 16 + 2 * c2] = r;
  }
}

// ---------------------------------------------------------------------------

extern "C" void kernel_launch(void* const* d_in, const int* in_sizes, int n_in,
                              void* d_out, int out_size, void* d_ws, size_t ws_size,
                              hipStream_t stream) {
  const float* x = (const float*)d_in[0];
  const int* ei = (const int*)d_in[1];
  const float* w1 = (const float*)d_in[2];
  const float* as1 = (const float*)d_in[3];
  const float* ad1 = (const float*)d_in[4];
  const float* b1 = (const float*)d_in[5];
  const float* w2 = (const float*)d_in[6];
  const float* as2 = (const float*)d_in[7];
  const float* ad2 = (const float*)d_in[8];
  const float* b2 = (const float*)d_in[9];
  float* out = (float*)d_out;

  int N = in_sizes[0] / 128;
  int E = in_sizes[1] / 2;
  const int* srcp = ei;
  const int* dstp = ei + E;

  int B = (N + (1 << BSHIFT) - 1) >> BSHIFT;  // 391 buckets (N<=65536 req'd)
  // bucket capacity: mean + 25% slack (+512), rounded to 256. Random dst ->
  // Poisson(mean), sigma ~64; slack ~16 sigma.
  int mean = (E + B - 1) / B;
  int CAP = (mean + mean / 4 + 512 + 255) & ~255;
  const int NB = 256;  // partition blocks
  int CH = (E + NB - 1) / NB;

  char* p = (char*)d_ws;
  auto alloc = [&](size_t bytes) -> void* {
    void* r = (void*)p;
    p += (bytes + 255) & ~(size_t)255;
    return r;
  };
  __half* xw1h = (__half*)alloc((size_t)N * 128 * 2);
  float* w1T = (float*)alloc(128 * 128 * 4);
  float* asrc1 = (float*)alloc((size_t)N * 2 * 4);
  float* adst1 = (float*)alloc((size_t)N * 2 * 4);
  __half* xw2h = (__half*)alloc((size_t)N * 16 * 2);
  float* asrc2 = (float*)alloc((size_t)N * 4);
  float* adst2 = (float*)alloc((size_t)N * 4);
  int2* nodeseg = (int2*)alloc((size_t)N * 8);
  int* csr = (int*)alloc((size_t)B * CAP * 4);
  unsigned* binned = (unsigned*)alloc((size_t)B * CAP * 4);
  int* bincur = (int*)alloc((size_t)B * 4);

  prep_kernel<<<64, 256, 0, stream>>>(w1, w1T, bincur, B, CAP);
  partition_kernel<<<NB, 256, 0, stream>>>(srcp, dstp, bincur, binned, E, B, CH);
  bucket_build_kernel<<<B, 256, 0, stream>>>(binned, bincur, nodeseg, csr, N, CAP);

  gemm1_kernel<<<(N + 31) / 32, 256, 0, stream>>>(x, w1T, as1, ad1, xw1h, asrc1, adst1, N);
  agg1_kernel<<<(N + 3) / 4, 256, 0, stream>>>(xw1h, asrc1, adst1, b1, w2, as2, ad2,
                                               csr, nodeseg, xw2h, asrc2, adst2, N);
  agg2_kernel<<<(N + 3) / 4, 256, 0, stream>>>(xw2h, asrc2, adst2, b2, csr, nodeseg, out, N);
}

// Round 9
// 227.351 us; speedup vs baseline: 1.0969x; 1.0969x over previous
//
#include <hip/hip_runtime.h>
#include <hip/hip_fp16.h>

// ---------------------------------------------------------------------------
// GAT 2-layer forward. N=50000 nodes, F=128, E=1.6M random edges (+N implicit
// self loops). L1: H=2,C=64 concat -> relu. L2: H=1,C=16.
//
// CSR build (atomic-minimized; measured: each device-scope atomicAdd costs a
// ~64B HBM write -> minimize COUNT, not locality). Fixed-capacity bucket
// segments: init_cursor -> partition (LDS hist + bulk reservation + packed
// scatter) -> bucket_build (all-LDS degree/scan/scatter; nodeseg=int2).
//
// gemm1: fp16 MFMA (mfma_f32_16x16x32_f16). A = x rows, B = w1 rows (w1 is
// [o][i] row-major = B^T layout, fed directly). Both staged to LDS fp16 with
// stride-136 rows (16B-aligned, conflict-free-enough). fp32 accumulate;
// epilogue stages C through LDS for coalesced fp16 stores + fused logits.
//
// agg1 fuses: softmax aggregation + relu + bias (h in registers) + gemm2
// (h @ w2^T) + layer-2 logits. agg1 is L2-miss-BW bound (measured: ~159MB
// fetch @ 2.5TB/s regardless of MLP) -> R7 8-edge loop kept (lowest VGPR).
// Softmax without max-shift (logits bounded, fp32 exp safe; ratio identical
// to reference in exact math). xw stored fp16 (2^-11 rel err).
// ---------------------------------------------------------------------------

#define BSHIFT 7                 // 128 dst nodes per bucket
#define MAXB 512                 // supports N <= 65536

using f16x8 = __attribute__((ext_vector_type(8))) _Float16;
using f16x4 = __attribute__((ext_vector_type(4))) _Float16;
using f32x4 = __attribute__((ext_vector_type(4))) float;

__device__ __forceinline__ float lrelu(float a) { return fmaxf(a, 0.2f * a); }

// ---------------- CSR build ----------------

__global__ __launch_bounds__(256) void init_cursor_kernel(int* __restrict__ bincur,
                                                          int B, int CAP) {
  int i = blockIdx.x * 256 + threadIdx.x;
  if (i < B) bincur[i] = i * CAP;
}

// partition edges into fixed-capacity bucket segments; packed 4B entries.
__global__ __launch_bounds__(256) void partition_kernel(const int* __restrict__ src,
                                                        const int* __restrict__ dst,
                                                        int* __restrict__ bincur,
                                                        unsigned* __restrict__ binned,
                                                        int E, int B, int CH) {
  __shared__ int s_h[MAXB];
  __shared__ int s_base[MAXB];
  __shared__ int s_cur[MAXB];
  for (int i = threadIdx.x; i < B; i += 256) s_h[i] = 0;
  __syncthreads();
  int lo = blockIdx.x * CH, hi = min(lo + CH, E);
  for (int e = lo + threadIdx.x; e < hi; e += 256)
    atomicAdd(&s_h[dst[e] >> BSHIFT], 1);
  __syncthreads();
  for (int i = threadIdx.x; i < B; i += 256) {
    int c = s_h[i];
    s_base[i] = c ? atomicAdd(&bincur[i], c) : 0;  // one bulk reservation
    s_cur[i] = 0;
  }
  __syncthreads();
  for (int e = lo + threadIdx.x; e < hi; e += 256) {
    int d = dst[e];
    int b = d >> BSHIFT;
    int r = atomicAdd(&s_cur[b], 1);
    binned[s_base[b] + r] = (unsigned)src[e] | ((unsigned)(d & 127) << 16);
  }
}

// one block per bucket: local degree/scan/scatter entirely in LDS.
__global__ __launch_bounds__(256) void bucket_build_kernel(const unsigned* __restrict__ binned,
                                                           const int* __restrict__ bincur,
                                                           int2* __restrict__ nodeseg,
                                                           int* __restrict__ csr,
                                                           int N, int CAP) {
  __shared__ int s_deg[128];
  __shared__ int s_cur[128];
  __shared__ int s_wsum;
  int b = blockIdx.x;
  int lo = b * CAP, hi = bincur[b];
  int t = threadIdx.x;
  if (t < 128) s_deg[t] = 0;
  __syncthreads();
  for (int i = lo + t; i < hi; i += 256)
    atomicAdd(&s_deg[binned[i] >> 16], 1);
  __syncthreads();
  int lane = t & 63, wv = t >> 6;
  int v = (t < 128) ? s_deg[t] : 0;
  int incl = v;
#pragma unroll
  for (int off = 1; off < 64; off <<= 1) {
    int u = __shfl_up(incl, off);
    if (lane >= off) incl += u;
  }
  if (t == 63) s_wsum = incl;  // wave-0 total
  __syncthreads();
  int excl = incl - v + ((wv == 1) ? s_wsum : 0);
  if (t < 128) {
    int node = (b << BSHIFT) + t;
    if (node < N) nodeseg[node] = make_int2(lo + excl, lo + excl + v);
    s_cur[t] = lo + excl;
  }
  __syncthreads();
  for (int i = lo + t; i < hi; i += 256) {
    unsigned e = binned[i];
    int p = atomicAdd(&s_cur[e >> 16], 1);  // LDS atomic
    csr[p] = (int)(e & 0xFFFFu);
  }
}

// ---------------- layer 1: fp16 MFMA GEMM + fused logits ----------------

// 64-node tile, 4 waves x 16 nodes. K=128 via 4 chunks of 32.
// LDS: x fp16 [64][136], w1 fp16 [128][136] (stride 136 halves = 272B).
#define XS 136
__global__ __launch_bounds__(256) void gemm1_kernel(const float* __restrict__ x,
                                                    const float* __restrict__ w1,
                                                    const float* __restrict__ as1,
                                                    const float* __restrict__ ad1,
                                                    __half* __restrict__ xw1h,
                                                    float* __restrict__ asrc1,
                                                    float* __restrict__ adst1, int N) {
  __shared__ __align__(16) _Float16 lx[64 * XS];
  __shared__ __align__(16) _Float16 lw[128 * XS];
  int t = threadIdx.x;
  int n0 = blockIdx.x * 64;

  // stage x: 64 rows x 32 float4 = 2048 -> 8 per thread
#pragma unroll
  for (int j = 0; j < 8; ++j) {
    int idx = t + 256 * j;
    int nd = idx >> 5, i4 = (idx & 31) * 4;
    int gn = n0 + nd;
    float4 v = (gn < N) ? *(const float4*)&x[(size_t)gn * 128 + i4]
                        : make_float4(0.f, 0.f, 0.f, 0.f);
    f16x4 h;
    h[0] = (_Float16)v.x; h[1] = (_Float16)v.y;
    h[2] = (_Float16)v.z; h[3] = (_Float16)v.w;
    *(f16x4*)&lx[nd * XS + i4] = h;
  }
  // stage w1 ([o][i] row-major = B^T): 128 rows x 32 float4 -> 16 per thread
#pragma unroll
  for (int j = 0; j < 16; ++j) {
    int idx = t + 256 * j;
    int o = idx >> 5, i4 = (idx & 31) * 4;
    float4 v = *(const float4*)&w1[(size_t)o * 128 + i4];
    f16x4 h;
    h[0] = (_Float16)v.x; h[1] = (_Float16)v.y;
    h[2] = (_Float16)v.z; h[3] = (_Float16)v.w;
    *(f16x4*)&lw[o * XS + i4] = h;
  }
  __syncthreads();

  int lane = t & 63, wv = t >> 6;
  int m16 = lane & 15, q = lane >> 4;  // A row / C col ; quad

  f32x4 acc[8];
#pragma unroll
  for (int i = 0; i < 8; ++i) acc[i] = (f32x4){0.f, 0.f, 0.f, 0.f};

#pragma unroll
  for (int c = 0; c < 4; ++c) {
    f16x8 a = *(const f16x8*)&lx[(16 * wv + m16) * XS + c * 32 + q * 8];
#pragma unroll
    for (int tt = 0; tt < 8; ++tt) {
      f16x8 b = *(const f16x8*)&lw[(tt * 16 + m16) * XS + c * 32 + q * 8];
      acc[tt] = __builtin_amdgcn_mfma_f32_16x16x32_f16(a, b, acc[tt], 0, 0, 0);
    }
  }

  // write C to this wave's own lx rows (wave-private; no barrier needed):
  // lane holds D[m=4q+r][o=tt*16+m16]
#pragma unroll
  for (int tt = 0; tt < 8; ++tt) {
#pragma unroll
    for (int r = 0; r < 4; ++r) {
      lx[(16 * wv + 4 * q + r) * XS + tt * 16 + m16] = (_Float16)acc[tt][r];
    }
  }

  // logits: lane -> node m16, o-part p = q (32 outputs each)
  {
    float ps = 0.f, pd = 0.f;
    int p = q;
#pragma unroll
    for (int k = 0; k < 4; ++k) {
      f16x8 hv = *(const f16x8*)&lx[(16 * wv + m16) * XS + p * 32 + k * 8];
      float4 s0 = *(const float4*)&as1[p * 32 + k * 8];
      float4 s1 = *(const float4*)&as1[p * 32 + k * 8 + 4];
      float4 d0 = *(const float4*)&ad1[p * 32 + k * 8];
      float4 d1 = *(const float4*)&ad1[p * 32 + k * 8 + 4];
      ps += (float)hv[0] * s0.x + (float)hv[1] * s0.y + (float)hv[2] * s0.z +
            (float)hv[3] * s0.w + (float)hv[4] * s1.x + (float)hv[5] * s1.y +
            (float)hv[6] * s1.z + (float)hv[7] * s1.w;
      pd += (float)hv[0] * d0.x + (float)hv[1] * d0.y + (float)hv[2] * d0.z +
            (float)hv[3] * d0.w + (float)hv[4] * d1.x + (float)hv[5] * d1.y +
            (float)hv[6] * d1.z + (float)hv[7] * d1.w;
    }
    // combine part pairs: p0+p1 -> head0, p2+p3 -> head1
    ps += __shfl_xor(ps, 16);
    pd += __shfl_xor(pd, 16);
    int n = n0 + 16 * wv + m16;
    if (n < N && (q == 0 || q == 2)) {
      int hh = q >> 1;
      asrc1[2 * n + hh] = ps;
      adst1[2 * n + hh] = pd;
    }
  }

  // coalesced fp16 stores: 16 rows x 16 uint4 per wave -> 4 per lane
#pragma unroll
  for (int i = 0; i < 4; ++i) {
    int m = q + 4 * i;
    int n = n0 + 16 * wv + m;
    if (n < N) {
      uint4 v = *(const uint4*)&lx[(16 * wv + m) * XS + m16 * 8];
      *(uint4*)&xw1h[(size_t)n * 128 + m16 * 8] = v;
    }
  }
}

// wave per dst node. 4 rows x 16 lanes x 16B (R7 8-edge loop, 2 loads in
// flight — measured: more MLP doesn't help, L2-miss BW bound). Epilogue
// fuses relu+bias+gemm2+layer-2 logits.
__global__ __launch_bounds__(256) void agg1_kernel(const __half* __restrict__ xw1h,
                                                   const float* __restrict__ asrc1,
                                                   const float* __restrict__ adst1,
                                                   const float* __restrict__ b1,
                                                   const float* __restrict__ w2,
                                                   const float* __restrict__ as2,
                                                   const float* __restrict__ ad2,
                                                   const int* __restrict__ csr,
                                                   const int2* __restrict__ nodeseg,
                                                   __half* __restrict__ xw2h,
                                                   float* __restrict__ asrc2,
                                                   float* __restrict__ adst2, int N) {
  __shared__ int s_off[4][64];    // row byte offset (s * 256)
  __shared__ float2 s_w[4][64];   // exp weights per head
  int lane = threadIdx.x & 63, wv = threadIdx.x >> 6;
  int d = blockIdx.x * 4 + wv;
  if (d >= N) return;
  int c8 = lane & 15;   // channels 8*c8 .. 8*c8+7
  int row = lane >> 4;  // 0..3 edge subgroup
  int head = c8 >> 3;   // head of these channels
  int2 seg = nodeseg[d];
  int e0 = seg.x, e1 = seg.y;
  float2 asv = *(const float2*)&asrc1[2 * d];
  float2 adv = *(const float2*)&adst1[2 * d];
  float wself = __expf(lrelu(head ? (asv.y + adv.y) : (asv.x + adv.x)));

  const char* xb = (const char*)xw1h + 16 * c8;  // channel base

  float a[8];
  float sum = 0.f;
#pragma unroll
  for (int k = 0; k < 8; ++k) a[k] = 0.f;
  if (row == 0) {  // self edge handled once, by row 0
    uint4 r = *(const uint4*)(xb + ((size_t)d << 8));
    const __half2* hp = (const __half2*)&r;
#pragma unroll
    for (int k = 0; k < 4; ++k) {
      float2 v = __half22float2(hp[k]);
      a[2 * k] = wself * v.x;
      a[2 * k + 1] = wself * v.y;
    }
    sum = wself;
  }

  for (int base = e0; base < e1; base += 64) {
    int cnt = min(64, e1 - base);
    if (lane < cnt) {
      int s = csr[base + lane];
      float2 aa = *(const float2*)&asrc1[2 * s];
      s_off[wv][lane] = s << 8;
      float2 w;
      w.x = __expf(lrelu(aa.x + adv.x));
      w.y = __expf(lrelu(aa.y + adv.y));
      s_w[wv][lane] = w;
    }
    // wave-private LDS: same wave wrote it; no barrier needed
    int j = 0;
    for (; j + 7 < cnt; j += 8) {
      int oA = s_off[wv][j + row];
      int oB = s_off[wv][j + 4 + row];
      float wA = ((const float*)&s_w[wv][j + row])[head];
      float wB = ((const float*)&s_w[wv][j + 4 + row])[head];
      uint4 rA = *(const uint4*)(xb + oA);
      uint4 rB = *(const uint4*)(xb + oB);
      const __half2* hA = (const __half2*)&rA;
      const __half2* hB = (const __half2*)&rB;
#pragma unroll
      for (int k = 0; k < 4; ++k) {
        float2 vA = __half22float2(hA[k]);
        float2 vB = __half22float2(hB[k]);
        a[2 * k] += wA * vA.x + wB * vB.x;
        a[2 * k + 1] += wA * vA.y + wB * vB.y;
      }
      sum += wA + wB;
    }
    for (; j < cnt; j += 4) {
      if (row < cnt - j) {
        int oA = s_off[wv][j + row];
        float wA = ((const float*)&s_w[wv][j + row])[head];
        uint4 rA = *(const uint4*)(xb + oA);
        const __half2* hA = (const __half2*)&rA;
#pragma unroll
        for (int k = 0; k < 4; ++k) {
          float2 vA = __half22float2(hA[k]);
          a[2 * k] += wA * vA.x;
          a[2 * k + 1] += wA * vA.y;
        }
        sum += wA;
      }
    }
  }

  // butterfly across the 4 rows -> every lane holds full sums for its c8
#pragma unroll
  for (int k = 0; k < 8; ++k) {
    a[k] += __shfl_xor(a[k], 16);
    a[k] += __shfl_xor(a[k], 32);
  }
  sum += __shfl_xor(sum, 16);
  sum += __shfl_xor(sum, 32);

  // h (relu'd, biased) in registers — every lane holds 8 channels
  float inv = 1.f / (sum + 1e-16f);
  float4 blo = *(const float4*)&b1[8 * c8];
  float4 bhi = *(const float4*)&b1[8 * c8 + 4];
  float h[8];
  h[0] = fmaxf(a[0] * inv + blo.x, 0.f);
  h[1] = fmaxf(a[1] * inv + blo.y, 0.f);
  h[2] = fmaxf(a[2] * inv + blo.z, 0.f);
  h[3] = fmaxf(a[3] * inv + blo.w, 0.f);
  h[4] = fmaxf(a[4] * inv + bhi.x, 0.f);
  h[5] = fmaxf(a[5] * inv + bhi.y, 0.f);
  h[6] = fmaxf(a[6] * inv + bhi.z, 0.f);
  h[7] = fmaxf(a[7] * inv + bhi.w, 0.f);

  // fused gemm2: row r computes xw2 channels r*4..r*4+3 (butterfly over 16)
  float p[4];
#pragma unroll
  for (int cc = 0; cc < 4; ++cc) {
    const float4 wlo = *(const float4*)&w2[(row * 4 + cc) * 128 + 8 * c8];
    const float4 whi = *(const float4*)&w2[(row * 4 + cc) * 128 + 8 * c8 + 4];
    p[cc] = h[0] * wlo.x + h[1] * wlo.y + h[2] * wlo.z + h[3] * wlo.w +
            h[4] * whi.x + h[5] * whi.y + h[6] * whi.z + h[7] * whi.w;
#pragma unroll
    for (int k = 1; k < 16; k <<= 1) p[cc] += __shfl_xor(p[cc], k);
  }
  float qs = 0.f, qd = 0.f;
#pragma unroll
  for (int cc = 0; cc < 4; ++cc) {
    qs += p[cc] * as2[row * 4 + cc];
    qd += p[cc] * ad2[row * 4 + cc];
  }
  qs += __shfl_xor(qs, 16);
  qs += __shfl_xor(qs, 32);
  qd += __shfl_xor(qd, 16);
  qd += __shfl_xor(qd, 32);
  if (lane == 0) {
    asrc2[d] = qs;
    adst2[d] = qd;
  }
  if (c8 == 0) {  // one lane per row stores its 4 channels (8B)
    union {
      __half hh[4];
      uint2 u;
    } pk;
#pragma unroll
    for (int cc = 0; cc < 4; ++cc) pk.hh[cc] = __float2half(p[cc]);
    *(uint2*)&xw2h[(size_t)d * 16 + row * 4] = pk.u;
  }
}

// wave per dst node. 8 rows x 8 lanes x 4B; 16-edge unroll = 2 loads in
// flight. Each lane owns 2 channels (half2).
__global__ __launch_bounds__(256) void agg2_kernel(const __half* __restrict__ xw2h,
                                                   const float* __restrict__ asrc2,
                                                   const float* __restrict__ adst2,
                                                   const float* __restrict__ b2,
                                                   const int* __restrict__ csr,
                                                   const int2* __restrict__ nodeseg,
                                                   float* __restrict__ out, int N) {
  __shared__ int s_off[4][64];   // row byte offset (s * 32)
  __shared__ float s_w[4][64];
  int lane = threadIdx.x & 63, wv = threadIdx.x >> 6;
  int d = blockIdx.x * 4 + wv;
  if (d >= N) return;
  int c2 = lane & 7;   // channels 2*c2, 2*c2+1
  int row = lane >> 3; // 0..7
  int2 seg = nodeseg[d];
  int e0 = seg.x, e1 = seg.y;
  float advd = adst2[d];
  float wself = __expf(lrelu(asrc2[d] + advd));
  const char* xb = (const char*)xw2h + 4 * c2;

  float a0 = 0.f, a1 = 0.f, sum = 0.f;
  if (row == 0) {
    float2 v = __half22float2(*(const __half2*)(xb + (size_t)d * 32));
    a0 = wself * v.x;
    a1 = wself * v.y;
    sum = wself;
  }
  for (int base = e0; base < e1; base += 64) {
    int cnt = min(64, e1 - base);
    if (lane < cnt) {
      int s = csr[base + lane];
      s_off[wv][lane] = s << 5;
      s_w[wv][lane] = __expf(lrelu(asrc2[s] + advd));
    }
    int j = 0;
    for (; j + 15 < cnt; j += 16) {
      int o0 = s_off[wv][j + row];
      int o1 = s_off[wv][j + 8 + row];
      float w0 = s_w[wv][j + row];
      float w1 = s_w[wv][j + 8 + row];
      float2 v0 = __half22float2(*(const __half2*)(xb + o0));
      float2 v1 = __half22float2(*(const __half2*)(xb + o1));
      a0 += w0 * v0.x + w1 * v1.x;
      a1 += w0 * v0.y + w1 * v1.y;
      sum += w0 + w1;
    }
    for (; j + 7 < cnt; j += 8) {
      int o0 = s_off[wv][j + row];
      float w0 = s_w[wv][j + row];
      float2 v0 = __half22float2(*(const __half2*)(xb + o0));
      a0 += w0 * v0.x;
      a1 += w0 * v0.y;
      sum += w0;
    }
    if (row < cnt - j) {  // tail: rows 0..cnt-j-1 take one edge each
      int o0 = s_off[wv][j + row];
      float w0 = s_w[wv][j + row];
      float2 v0 = __half22float2(*(const __half2*)(xb + o0));
      a0 += w0 * v0.x;
      a1 += w0 * v0.y;
      sum += w0;
    }
  }
#pragma unroll
  for (int k = 8; k < 64; k <<= 1) {
    a0 += __shfl_xor(a0, k);
    a1 += __shfl_xor(a1, k);
    sum += __shfl_xor(sum, k);
  }
  if (lane < 8) {
    float inv = 1.f / (sum + 1e-16f);
    float2 r;
    r.x = a0 * inv + b2[2 * c2];
    r.y = a1 * inv + b2[2 * c2 + 1];
    *(float2*)&out[(size_t)d * 16 + 2 * c2] = r;
  }
}

// ---------------------------------------------------------------------------

extern "C" void kernel_launch(void* const* d_in, const int* in_sizes, int n_in,
                              void* d_out, int out_size, void* d_ws, size_t ws_size,
                              hipStream_t stream) {
  const float* x = (const float*)d_in[0];
  const int* ei = (const int*)d_in[1];
  const float* w1 = (const float*)d_in[2];
  const float* as1 = (const float*)d_in[3];
  const float* ad1 = (const float*)d_in[4];
  const float* b1 = (const float*)d_in[5];
  const float* w2 = (const float*)d_in[6];
  const float* as2 = (const float*)d_in[7];
  const float* ad2 = (const float*)d_in[8];
  const float* b2 = (const float*)d_in[9];
  float* out = (float*)d_out;

  int N = in_sizes[0] / 128;
  int E = in_sizes[1] / 2;
  const int* srcp = ei;
  const int* dstp = ei + E;

  int B = (N + (1 << BSHIFT) - 1) >> BSHIFT;  // 391 buckets (N<=65536 req'd)
  // bucket capacity: mean + 25% slack (+512), rounded to 256 (Poisson ~16sig)
  int mean = (E + B - 1) / B;
  int CAP = (mean + mean / 4 + 512 + 255) & ~255;
  const int NB = 256;  // partition blocks
  int CH = (E + NB - 1) / NB;

  char* p = (char*)d_ws;
  auto alloc = [&](size_t bytes) -> void* {
    void* r = (void*)p;
    p += (bytes + 255) & ~(size_t)255;
    return r;
  };
  __half* xw1h = (__half*)alloc((size_t)N * 128 * 2);
  float* asrc1 = (float*)alloc((size_t)N * 2 * 4);
  float* adst1 = (float*)alloc((size_t)N * 2 * 4);
  __half* xw2h = (__half*)alloc((size_t)N * 16 * 2);
  float* asrc2 = (float*)alloc((size_t)N * 4);
  float* adst2 = (float*)alloc((size_t)N * 4);
  int2* nodeseg = (int2*)alloc((size_t)N * 8);
  int* csr = (int*)alloc((size_t)B * CAP * 4);
  unsigned* binned = (unsigned*)alloc((size_t)B * CAP * 4);
  int* bincur = (int*)alloc((size_t)B * 4);

  init_cursor_kernel<<<(B + 255) / 256, 256, 0, stream>>>(bincur, B, CAP);
  partition_kernel<<<NB, 256, 0, stream>>>(srcp, dstp, bincur, binned, E, B, CH);
  bucket_build_kernel<<<B, 256, 0, stream>>>(binned, bincur, nodeseg, csr, N, CAP);

  gemm1_kernel<<<(N + 63) / 64, 256, 0, stream>>>(x, w1, as1, ad1, xw1h, asrc1, adst1, N);
  agg1_kernel<<<(N + 3) / 4, 256, 0, stream>>>(xw1h, asrc1, adst1, b1, w2, as2, ad2,
                                               csr, nodeseg, xw2h, asrc2, adst2, N);
  agg2_kernel<<<(N + 3) / 4, 256, 0, stream>>>(xw2h, asrc2, adst2, b2, csr, nodeseg, out, N);
}

// Round 10
// 222.920 us; speedup vs baseline: 1.1187x; 1.0199x over previous
//
#include <hip/hip_runtime.h>
#include <hip/hip_fp16.h>

// ---------------------------------------------------------------------------
// GAT 2-layer forward. N=50000 nodes, F=128, E=1.6M random edges (+N implicit
// self loops). L1: H=2,C=64 concat -> relu. L2: H=1,C=16.
//
// CSR build (atomic-minimized; measured: each device-scope atomicAdd costs a
// ~64B HBM write -> minimize COUNT, not locality). Fixed-capacity bucket
// segments; bincur zeroed via memset, reservations biased by b*CAP.
// Dispatches: memset -> {partition || gemm1} (block-range fused) ->
// bucket_build (LDS-staged edges; csr stored as ushort) -> agg1 -> agg2.
//
// gemm1: fp16 MFMA (mfma_f32_16x16x32_f16), A=x rows, B=w1 rows ([o][i] =
// B^T fed directly), LDS stride-136 fp16, fp32 accumulate, epilogue stages C
// through LDS for coalesced fp16 stores + fused logits.
//
// agg1 fuses: softmax aggregation + relu + bias (h in registers) + gemm2
// (h @ w2^T) + layer-2 logits. agg1 is gather-traffic bound (measured:
// ~159MB fetch @ ~2.5TB/s regardless of MLP depth) — structural floor.
// Softmax without max-shift (logits bounded, fp32 exp safe; ratio identical
// to reference in exact math). xw stored fp16 (2^-11 rel err).
// ---------------------------------------------------------------------------

#define BSHIFT 7                 // 128 dst nodes per bucket
#define MAXB 512                 // supports N <= 65536
#define CAPMAX 6144              // LDS edge-staging bound (entries)
#define XS 136

using f16x8 = __attribute__((ext_vector_type(8))) _Float16;
using f16x4 = __attribute__((ext_vector_type(4))) _Float16;
using f32x4 = __attribute__((ext_vector_type(4))) float;

__device__ __forceinline__ float lrelu(float a) { return fmaxf(a, 0.2f * a); }

// ---------------- fused: partition (blocks 0..NB-1) + gemm1 (rest) --------

__global__ __launch_bounds__(256) void part_gemm1_kernel(
    const int* __restrict__ src, const int* __restrict__ dst,
    int* __restrict__ bincur, unsigned* __restrict__ binned,
    int E, int B, int CH, int CAP, int NB,
    const float* __restrict__ x, const float* __restrict__ w1,
    const float* __restrict__ as1, const float* __restrict__ ad1,
    __half* __restrict__ xw1h, float* __restrict__ asrc1,
    float* __restrict__ adst1, int N) {
  __shared__ __align__(16) char smem[(64 + 128) * XS * 2];  // 52224 B
  int t = threadIdx.x;

  if (blockIdx.x < (unsigned)NB) {
    // ---- partition: LDS hist -> bulk reservation -> packed scatter ----
    int* s_h = (int*)smem;
    int* s_base = s_h + MAXB;
    int* s_cur = s_base + MAXB;
    for (int i = t; i < B; i += 256) s_h[i] = 0;
    __syncthreads();
    int lo = blockIdx.x * CH, hi = min(lo + CH, E);
    for (int e = lo + t; e < hi; e += 256)
      atomicAdd(&s_h[dst[e] >> BSHIFT], 1);
    __syncthreads();
    for (int i = t; i < B; i += 256) {
      int c = s_h[i];
      s_base[i] = c ? (i * CAP + atomicAdd(&bincur[i], c)) : 0;
      s_cur[i] = 0;
    }
    __syncthreads();
    for (int e = lo + t; e < hi; e += 256) {
      int d = dst[e];
      int b = d >> BSHIFT;
      int r = atomicAdd(&s_cur[b], 1);
      binned[s_base[b] + r] = (unsigned)src[e] | ((unsigned)(d & 127) << 16);
    }
    return;
  }

  // ---- gemm1: 64-node tile, fp16 MFMA, fused logits ----
  _Float16* lx = (_Float16*)smem;
  _Float16* lw = lx + 64 * XS;
  int n0 = (blockIdx.x - NB) * 64;

#pragma unroll
  for (int j = 0; j < 8; ++j) {
    int idx = t + 256 * j;
    int nd = idx >> 5, i4 = (idx & 31) * 4;
    int gn = n0 + nd;
    float4 v = (gn < N) ? *(const float4*)&x[(size_t)gn * 128 + i4]
                        : make_float4(0.f, 0.f, 0.f, 0.f);
    f16x4 h;
    h[0] = (_Float16)v.x; h[1] = (_Float16)v.y;
    h[2] = (_Float16)v.z; h[3] = (_Float16)v.w;
    *(f16x4*)&lx[nd * XS + i4] = h;
  }
#pragma unroll
  for (int j = 0; j < 16; ++j) {
    int idx = t + 256 * j;
    int o = idx >> 5, i4 = (idx & 31) * 4;
    float4 v = *(const float4*)&w1[(size_t)o * 128 + i4];
    f16x4 h;
    h[0] = (_Float16)v.x; h[1] = (_Float16)v.y;
    h[2] = (_Float16)v.z; h[3] = (_Float16)v.w;
    *(f16x4*)&lw[o * XS + i4] = h;
  }
  __syncthreads();

  int lane = t & 63, wv = t >> 6;
  int m16 = lane & 15, q = lane >> 4;

  f32x4 acc[8];
#pragma unroll
  for (int i = 0; i < 8; ++i) acc[i] = (f32x4){0.f, 0.f, 0.f, 0.f};

#pragma unroll
  for (int c = 0; c < 4; ++c) {
    f16x8 a = *(const f16x8*)&lx[(16 * wv + m16) * XS + c * 32 + q * 8];
#pragma unroll
    for (int tt = 0; tt < 8; ++tt) {
      f16x8 b = *(const f16x8*)&lw[(tt * 16 + m16) * XS + c * 32 + q * 8];
      acc[tt] = __builtin_amdgcn_mfma_f32_16x16x32_f16(a, b, acc[tt], 0, 0, 0);
    }
  }

  // write C to this wave's own lx rows (wave-private; no barrier needed)
#pragma unroll
  for (int tt = 0; tt < 8; ++tt) {
#pragma unroll
    for (int r = 0; r < 4; ++r) {
      lx[(16 * wv + 4 * q + r) * XS + tt * 16 + m16] = (_Float16)acc[tt][r];
    }
  }

  // logits: lane -> node m16, o-part p = q (32 outputs each)
  {
    float ps = 0.f, pd = 0.f;
    int p = q;
#pragma unroll
    for (int k = 0; k < 4; ++k) {
      f16x8 hv = *(const f16x8*)&lx[(16 * wv + m16) * XS + p * 32 + k * 8];
      float4 s0 = *(const float4*)&as1[p * 32 + k * 8];
      float4 s1 = *(const float4*)&as1[p * 32 + k * 8 + 4];
      float4 d0 = *(const float4*)&ad1[p * 32 + k * 8];
      float4 d1 = *(const float4*)&ad1[p * 32 + k * 8 + 4];
      ps += (float)hv[0] * s0.x + (float)hv[1] * s0.y + (float)hv[2] * s0.z +
            (float)hv[3] * s0.w + (float)hv[4] * s1.x + (float)hv[5] * s1.y +
            (float)hv[6] * s1.z + (float)hv[7] * s1.w;
      pd += (float)hv[0] * d0.x + (float)hv[1] * d0.y + (float)hv[2] * d0.z +
            (float)hv[3] * d0.w + (float)hv[4] * d1.x + (float)hv[5] * d1.y +
            (float)hv[6] * d1.z + (float)hv[7] * d1.w;
    }
    ps += __shfl_xor(ps, 16);
    pd += __shfl_xor(pd, 16);
    int n = n0 + 16 * wv + m16;
    if (n < N && (q == 0 || q == 2)) {
      int hh = q >> 1;
      asrc1[2 * n + hh] = ps;
      adst1[2 * n + hh] = pd;
    }
  }

  // coalesced fp16 stores: 16 rows x 16 uint4 per wave -> 4 per lane
#pragma unroll
  for (int i = 0; i < 4; ++i) {
    int m = q + 4 * i;
    int n = n0 + 16 * wv + m;
    if (n < N) {
      uint4 v = *(const uint4*)&lx[(16 * wv + m) * XS + m16 * 8];
      *(uint4*)&xw1h[(size_t)n * 128 + m16 * 8] = v;
    }
  }
}

// ---------------- bucket_build: all-LDS, staged edges, ushort csr ---------

__global__ __launch_bounds__(256) void bucket_build_kernel(const unsigned* __restrict__ binned,
                                                           const int* __restrict__ bincur,
                                                           int2* __restrict__ nodeseg,
                                                           unsigned short* __restrict__ csr,
                                                           int N, int CAP) {
  __shared__ int s_deg[128];
  __shared__ int s_cur[128];
  __shared__ int s_wsum;
  __shared__ unsigned s_edges[CAPMAX];
  int b = blockIdx.x;
  int lo = b * CAP, hi = lo + bincur[b];
  int cnt = hi - lo;
  int t = threadIdx.x;
  if (t < 128) s_deg[t] = 0;
  int stg = min(cnt, CAPMAX);
  for (int i = t; i < stg; i += 256) s_edges[i] = binned[lo + i];
  __syncthreads();
  for (int i = t; i < cnt; i += 256) {
    unsigned e = (i < CAPMAX) ? s_edges[i] : binned[lo + i];
    atomicAdd(&s_deg[e >> 16], 1);
  }
  __syncthreads();
  int lane = t & 63, wv = t >> 6;
  int v = (t < 128) ? s_deg[t] : 0;
  int incl = v;
#pragma unroll
  for (int off = 1; off < 64; off <<= 1) {
    int u = __shfl_up(incl, off);
    if (lane >= off) incl += u;
  }
  if (t == 63) s_wsum = incl;  // wave-0 total
  __syncthreads();
  int excl = incl - v + ((wv == 1) ? s_wsum : 0);
  if (t < 128) {
    int node = (b << BSHIFT) + t;
    if (node < N) nodeseg[node] = make_int2(lo + excl, lo + excl + v);
    s_cur[t] = lo + excl;
  }
  __syncthreads();
  for (int i = t; i < cnt; i += 256) {
    unsigned e = (i < CAPMAX) ? s_edges[i] : binned[lo + i];
    int p = atomicAdd(&s_cur[e >> 16], 1);  // LDS atomic
    csr[p] = (unsigned short)(e & 0xFFFFu);
  }
}

// ---------------- agg1: aggregation + fused relu/bias/gemm2/logits --------

// wave per dst node. 4 rows x 16 lanes x 16B (8-edge loop, 2 loads in
// flight — measured: L2-miss BW bound; deeper MLP doesn't help).
__global__ __launch_bounds__(256) void agg1_kernel(const __half* __restrict__ xw1h,
                                                   const float* __restrict__ asrc1,
                                                   const float* __restrict__ adst1,
                                                   const float* __restrict__ b1,
                                                   const float* __restrict__ w2,
                                                   const float* __restrict__ as2,
                                                   const float* __restrict__ ad2,
                                                   const unsigned short* __restrict__ csr,
                                                   const int2* __restrict__ nodeseg,
                                                   __half* __restrict__ xw2h,
                                                   float* __restrict__ asrc2,
                                                   float* __restrict__ adst2, int N) {
  __shared__ int s_off[4][64];    // row byte offset (s * 256)
  __shared__ float2 s_w[4][64];   // exp weights per head
  int lane = threadIdx.x & 63, wv = threadIdx.x >> 6;
  int d = blockIdx.x * 4 + wv;
  if (d >= N) return;
  int c8 = lane & 15;   // channels 8*c8 .. 8*c8+7
  int row = lane >> 4;  // 0..3 edge subgroup
  int head = c8 >> 3;   // head of these channels
  int2 seg = nodeseg[d];
  int e0 = seg.x, e1 = seg.y;
  float2 asv = *(const float2*)&asrc1[2 * d];
  float2 adv = *(const float2*)&adst1[2 * d];
  float wself = __expf(lrelu(head ? (asv.y + adv.y) : (asv.x + adv.x)));

  const char* xb = (const char*)xw1h + 16 * c8;  // channel base

  float a[8];
  float sum = 0.f;
#pragma unroll
  for (int k = 0; k < 8; ++k) a[k] = 0.f;
  if (row == 0) {  // self edge handled once, by row 0
    uint4 r = *(const uint4*)(xb + ((size_t)d << 8));
    const __half2* hp = (const __half2*)&r;
#pragma unroll
    for (int k = 0; k < 4; ++k) {
      float2 v = __half22float2(hp[k]);
      a[2 * k] = wself * v.x;
      a[2 * k + 1] = wself * v.y;
    }
    sum = wself;
  }

  for (int base = e0; base < e1; base += 64) {
    int cnt = min(64, e1 - base);
    if (lane < cnt) {
      int s = (int)csr[base + lane];
      float2 aa = *(const float2*)&asrc1[2 * s];
      s_off[wv][lane] = s << 8;
      float2 w;
      w.x = __expf(lrelu(aa.x + adv.x));
      w.y = __expf(lrelu(aa.y + adv.y));
      s_w[wv][lane] = w;
    }
    // wave-private LDS: same wave wrote it; no barrier needed
    int j = 0;
    for (; j + 7 < cnt; j += 8) {
      int oA = s_off[wv][j + row];
      int oB = s_off[wv][j + 4 + row];
      float wA = ((const float*)&s_w[wv][j + row])[head];
      float wB = ((const float*)&s_w[wv][j + 4 + row])[head];
      uint4 rA = *(const uint4*)(xb + oA);
      uint4 rB = *(const uint4*)(xb + oB);
      const __half2* hA = (const __half2*)&rA;
      const __half2* hB = (const __half2*)&rB;
#pragma unroll
      for (int k = 0; k < 4; ++k) {
        float2 vA = __half22float2(hA[k]);
        float2 vB = __half22float2(hB[k]);
        a[2 * k] += wA * vA.x + wB * vB.x;
        a[2 * k + 1] += wA * vA.y + wB * vB.y;
      }
      sum += wA + wB;
    }
    for (; j < cnt; j += 4) {
      if (row < cnt - j) {
        int oA = s_off[wv][j + row];
        float wA = ((const float*)&s_w[wv][j + row])[head];
        uint4 rA = *(const uint4*)(xb + oA);
        const __half2* hA = (const __half2*)&rA;
#pragma unroll
        for (int k = 0; k < 4; ++k) {
          float2 vA = __half22float2(hA[k]);
          a[2 * k] += wA * vA.x;
          a[2 * k + 1] += wA * vA.y;
        }
        sum += wA;
      }
    }
  }

  // butterfly across the 4 rows -> every lane holds full sums for its c8
#pragma unroll
  for (int k = 0; k < 8; ++k) {
    a[k] += __shfl_xor(a[k], 16);
    a[k] += __shfl_xor(a[k], 32);
  }
  sum += __shfl_xor(sum, 16);
  sum += __shfl_xor(sum, 32);

  // h (relu'd, biased) in registers — every lane holds 8 channels
  float inv = 1.f / (sum + 1e-16f);
  float4 blo = *(const float4*)&b1[8 * c8];
  float4 bhi = *(const float4*)&b1[8 * c8 + 4];
  float h[8];
  h[0] = fmaxf(a[0] * inv + blo.x, 0.f);
  h[1] = fmaxf(a[1] * inv + blo.y, 0.f);
  h[2] = fmaxf(a[2] * inv + blo.z, 0.f);
  h[3] = fmaxf(a[3] * inv + blo.w, 0.f);
  h[4] = fmaxf(a[4] * inv + bhi.x, 0.f);
  h[5] = fmaxf(a[5] * inv + bhi.y, 0.f);
  h[6] = fmaxf(a[6] * inv + bhi.z, 0.f);
  h[7] = fmaxf(a[7] * inv + bhi.w, 0.f);

  // fused gemm2: row r computes xw2 channels r*4..r*4+3 (butterfly over 16)
  float p[4];
#pragma unroll
  for (int cc = 0; cc < 4; ++cc) {
    const float4 wlo = *(const float4*)&w2[(row * 4 + cc) * 128 + 8 * c8];
    const float4 whi = *(const float4*)&w2[(row * 4 + cc) * 128 + 8 * c8 + 4];
    p[cc] = h[0] * wlo.x + h[1] * wlo.y + h[2] * wlo.z + h[3] * wlo.w +
            h[4] * whi.x + h[5] * whi.y + h[6] * whi.z + h[7] * whi.w;
#pragma unroll
    for (int k = 1; k < 16; k <<= 1) p[cc] += __shfl_xor(p[cc], k);
  }
  float qs = 0.f, qd = 0.f;
#pragma unroll
  for (int cc = 0; cc < 4; ++cc) {
    qs += p[cc] * as2[row * 4 + cc];
    qd += p[cc] * ad2[row * 4 + cc];
  }
  qs += __shfl_xor(qs, 16);
  qs += __shfl_xor(qs, 32);
  qd += __shfl_xor(qd, 16);
  qd += __shfl_xor(qd, 32);
  if (lane == 0) {
    asrc2[d] = qs;
    adst2[d] = qd;
  }
  if (c8 == 0) {  // one lane per row stores its 4 channels (8B)
    union {
      __half hh[4];
      uint2 u;
    } pk;
#pragma unroll
    for (int cc = 0; cc < 4; ++cc) pk.hh[cc] = __float2half(p[cc]);
    *(uint2*)&xw2h[(size_t)d * 16 + row * 4] = pk.u;
  }
}

// ---------------- agg2 ----------------

// wave per dst node. 8 rows x 8 lanes x 4B; 16-edge unroll = 2 loads in
// flight. Each lane owns 2 channels (half2).
__global__ __launch_bounds__(256) void agg2_kernel(const __half* __restrict__ xw2h,
                                                   const float* __restrict__ asrc2,
                                                   const float* __restrict__ adst2,
                                                   const float* __restrict__ b2,
                                                   const unsigned short* __restrict__ csr,
                                                   const int2* __restrict__ nodeseg,
                                                   float* __restrict__ out, int N) {
  __shared__ int s_off[4][64];   // row byte offset (s * 32)
  __shared__ float s_w[4][64];
  int lane = threadIdx.x & 63, wv = threadIdx.x >> 6;
  int d = blockIdx.x * 4 + wv;
  if (d >= N) return;
  int c2 = lane & 7;   // channels 2*c2, 2*c2+1
  int row = lane >> 3; // 0..7
  int2 seg = nodeseg[d];
  int e0 = seg.x, e1 = seg.y;
  float advd = adst2[d];
  float wself = __expf(lrelu(asrc2[d] + advd));
  const char* xb = (const char*)xw2h + 4 * c2;

  float a0 = 0.f, a1 = 0.f, sum = 0.f;
  if (row == 0) {
    float2 v = __half22float2(*(const __half2*)(xb + (size_t)d * 32));
    a0 = wself * v.x;
    a1 = wself * v.y;
    sum = wself;
  }
  for (int base = e0; base < e1; base += 64) {
    int cnt = min(64, e1 - base);
    if (lane < cnt) {
      int s = (int)csr[base + lane];
      s_off[wv][lane] = s << 5;
      s_w[wv][lane] = __expf(lrelu(asrc2[s] + advd));
    }
    int j = 0;
    for (; j + 15 < cnt; j += 16) {
      int o0 = s_off[wv][j + row];
      int o1 = s_off[wv][j + 8 + row];
      float w0 = s_w[wv][j + row];
      float w1 = s_w[wv][j + 8 + row];
      float2 v0 = __half22float2(*(const __half2*)(xb + o0));
      float2 v1 = __half22float2(*(const __half2*)(xb + o1));
      a0 += w0 * v0.x + w1 * v1.x;
      a1 += w0 * v0.y + w1 * v1.y;
      sum += w0 + w1;
    }
    for (; j + 7 < cnt; j += 8) {
      int o0 = s_off[wv][j + row];
      float w0 = s_w[wv][j + row];
      float2 v0 = __half22float2(*(const __half2*)(xb + o0));
      a0 += w0 * v0.x;
      a1 += w0 * v0.y;
      sum += w0;
    }
    if (row < cnt - j) {  // tail: rows 0..cnt-j-1 take one edge each
      int o0 = s_off[wv][j + row];
      float w0 = s_w[wv][j + row];
      float2 v0 = __half22float2(*(const __half2*)(xb + o0));
      a0 += w0 * v0.x;
      a1 += w0 * v0.y;
      sum += w0;
    }
  }
#pragma unroll
  for (int k = 8; k < 64; k <<= 1) {
    a0 += __shfl_xor(a0, k);
    a1 += __shfl_xor(a1, k);
    sum += __shfl_xor(sum, k);
  }
  if (lane < 8) {
    float inv = 1.f / (sum + 1e-16f);
    float2 r;
    r.x = a0 * inv + b2[2 * c2];
    r.y = a1 * inv + b2[2 * c2 + 1];
    *(float2*)&out[(size_t)d * 16 + 2 * c2] = r;
  }
}

// ---------------------------------------------------------------------------

extern "C" void kernel_launch(void* const* d_in, const int* in_sizes, int n_in,
                              void* d_out, int out_size, void* d_ws, size_t ws_size,
                              hipStream_t stream) {
  const float* x = (const float*)d_in[0];
  const int* ei = (const int*)d_in[1];
  const float* w1 = (const float*)d_in[2];
  const float* as1 = (const float*)d_in[3];
  const float* ad1 = (const float*)d_in[4];
  const float* b1 = (const float*)d_in[5];
  const float* w2 = (const float*)d_in[6];
  const float* as2 = (const float*)d_in[7];
  const float* ad2 = (const float*)d_in[8];
  const float* b2 = (const float*)d_in[9];
  float* out = (float*)d_out;

  int N = in_sizes[0] / 128;
  int E = in_sizes[1] / 2;
  const int* srcp = ei;
  const int* dstp = ei + E;

  int B = (N + (1 << BSHIFT) - 1) >> BSHIFT;  // 391 buckets (N<=65536 req'd)
  // bucket capacity: mean + 25% slack (+512), rounded to 256 (Poisson ~16sig)
  int mean = (E + B - 1) / B;
  int CAP = (mean + mean / 4 + 512 + 255) & ~255;
  const int NB = 256;  // partition blocks
  int CH = (E + NB - 1) / NB;
  int GB = (N + 63) / 64;  // gemm1 tiles

  char* p = (char*)d_ws;
  auto alloc = [&](size_t bytes) -> void* {
    void* r = (void*)p;
    p += (bytes + 255) & ~(size_t)255;
    return r;
  };
  __half* xw1h = (__half*)alloc((size_t)N * 128 * 2);
  float* asrc1 = (float*)alloc((size_t)N * 2 * 4);
  float* adst1 = (float*)alloc((size_t)N * 2 * 4);
  __half* xw2h = (__half*)alloc((size_t)N * 16 * 2);
  float* asrc2 = (float*)alloc((size_t)N * 4);
  float* adst2 = (float*)alloc((size_t)N * 4);
  int2* nodeseg = (int2*)alloc((size_t)N * 8);
  unsigned short* csr = (unsigned short*)alloc((size_t)B * CAP * 2);
  unsigned* binned = (unsigned*)alloc((size_t)B * CAP * 4);
  int* bincur = (int*)alloc((size_t)B * 4);

  hipMemsetAsync(bincur, 0, (size_t)B * 4, stream);
  part_gemm1_kernel<<<NB + GB, 256, 0, stream>>>(srcp, dstp, bincur, binned,
                                                 E, B, CH, CAP, NB,
                                                 x, w1, as1, ad1, xw1h, asrc1, adst1, N);
  bucket_build_kernel<<<B, 256, 0, stream>>>(binned, bincur, nodeseg, csr, N, CAP);
  agg1_kernel<<<(N + 3) / 4, 256, 0, stream>>>(xw1h, asrc1, adst1, b1, w2, as2, ad2,
                                               csr, nodeseg, xw2h, asrc2, adst2, N);
  agg2_kernel<<<(N + 3) / 4, 256, 0, stream>>>(xw2h, asrc2, adst2, b2, csr, nodeseg, out, N);
}

// Round 11
// 211.827 us; speedup vs baseline: 1.1773x; 1.0524x over previous
//
#include <hip/hip_runtime.h>
#include <hip/hip_fp16.h>

// ---------------------------------------------------------------------------
// GAT 2-layer forward. N=50000 nodes, F=128, E=1.6M random edges (+N implicit
// self loops). L1: H=2,C=64 concat -> relu. L2: H=1,C=16.
//
// CSR build (atomic-minimized; measured: each device-scope atomicAdd costs a
// ~64B HBM write -> minimize COUNT, not locality). Fixed-capacity bucket
// segments; bincur zeroed via memset, reservations biased by b*CAP.
// Dispatches: memset -> {partition || gemm1} (block-range fused) ->
// bucket_build (LDS-staged edges; csr stored as ushort) -> agg1 -> agg2.
//
// partition is SINGLE-global-pass: edges packed into LDS words
// (src | (d&127)<<16 | (d>>7)<<23; bucket id fits the spare 9 bits since
// B<512) during the histogram pass; the rank+scatter pass runs from LDS.
//
// gemm1: fp16 MFMA (mfma_f32_16x16x32_f16), A=x rows, B=w1 rows ([o][i] =
// B^T fed directly), LDS stride-136 fp16, fp32 accumulate, epilogue stages C
// through LDS for coalesced fp16 stores + fused logits.
//
// agg1 fuses: softmax aggregation + relu + bias (h in registers) + gemm2
// (h @ w2^T) + layer-2 logits. agg1 is gather-traffic bound (measured:
// ~157MB fetch @ ~2.5TB/s regardless of MLP depth/width/occupancy) —
// structural floor for this layout.
// Softmax without max-shift (logits bounded, fp32 exp safe; ratio identical
// to reference in exact math). xw stored fp16 (2^-11 rel err).
// ---------------------------------------------------------------------------

#define BSHIFT 7                 // 128 dst nodes per bucket
#define MAXB 512                 // supports N <= 65536
#define CAPMAX 6144              // LDS edge-staging bound (entries)
#define XS 136

using f16x8 = __attribute__((ext_vector_type(8))) _Float16;
using f16x4 = __attribute__((ext_vector_type(4))) _Float16;
using f32x4 = __attribute__((ext_vector_type(4))) float;

__device__ __forceinline__ float lrelu(float a) { return fmaxf(a, 0.2f * a); }

// ---------------- fused: partition (blocks 0..NB-1) + gemm1 (rest) --------

__global__ __launch_bounds__(256) void part_gemm1_kernel(
    const int* __restrict__ src, const int* __restrict__ dst,
    int* __restrict__ bincur, unsigned* __restrict__ binned,
    int E, int B, int CH, int CAP, int NB,
    const float* __restrict__ x, const float* __restrict__ w1,
    const float* __restrict__ as1, const float* __restrict__ ad1,
    __half* __restrict__ xw1h, float* __restrict__ asrc1,
    float* __restrict__ adst1, int N) {
  __shared__ __align__(16) char smem[(64 + 128) * XS * 2];  // 52224 B
  int t = threadIdx.x;

  if (blockIdx.x < (unsigned)NB) {
    // ---- partition: single global pass. Pack edges into LDS during the
    // histogram pass; rank+scatter pass runs entirely from LDS. ----
    int* s_h = (int*)smem;
    int* s_base = s_h + MAXB;
    int* s_cur = s_base + MAXB;
    unsigned* s_pack = (unsigned*)(s_cur + MAXB);  // CH <= 6250 -> 25 KB
    for (int i = t; i < B; i += 256) s_h[i] = 0;
    __syncthreads();
    int lo = blockIdx.x * CH;
    int cnt = min(CH, E - lo);
    for (int i = t; i < cnt; i += 256) {
      int d = dst[lo + i];
      int s = src[lo + i];
      atomicAdd(&s_h[d >> BSHIFT], 1);
      s_pack[i] = (unsigned)s | ((unsigned)(d & 127) << 16) |
                  ((unsigned)(d >> BSHIFT) << 23);
    }
    __syncthreads();
    for (int i = t; i < B; i += 256) {
      int c = s_h[i];
      s_base[i] = c ? (i * CAP + atomicAdd(&bincur[i], c)) : 0;
      s_cur[i] = 0;
    }
    __syncthreads();
    for (int i = t; i < cnt; i += 256) {
      unsigned e = s_pack[i];
      int b = e >> 23;
      int r = atomicAdd(&s_cur[b], 1);
      binned[s_base[b] + r] = e & 0x7FFFFFu;
    }
    return;
  }

  // ---- gemm1: 64-node tile, fp16 MFMA, fused logits ----
  _Float16* lx = (_Float16*)smem;
  _Float16* lw = lx + 64 * XS;
  int n0 = (blockIdx.x - NB) * 64;

#pragma unroll
  for (int j = 0; j < 8; ++j) {
    int idx = t + 256 * j;
    int nd = idx >> 5, i4 = (idx & 31) * 4;
    int gn = n0 + nd;
    float4 v = (gn < N) ? *(const float4*)&x[(size_t)gn * 128 + i4]
                        : make_float4(0.f, 0.f, 0.f, 0.f);
    f16x4 h;
    h[0] = (_Float16)v.x; h[1] = (_Float16)v.y;
    h[2] = (_Float16)v.z; h[3] = (_Float16)v.w;
    *(f16x4*)&lx[nd * XS + i4] = h;
  }
#pragma unroll
  for (int j = 0; j < 16; ++j) {
    int idx = t + 256 * j;
    int o = idx >> 5, i4 = (idx & 31) * 4;
    float4 v = *(const float4*)&w1[(size_t)o * 128 + i4];
    f16x4 h;
    h[0] = (_Float16)v.x; h[1] = (_Float16)v.y;
    h[2] = (_Float16)v.z; h[3] = (_Float16)v.w;
    *(f16x4*)&lw[o * XS + i4] = h;
  }
  __syncthreads();

  int lane = t & 63, wv = t >> 6;
  int m16 = lane & 15, q = lane >> 4;

  f32x4 acc[8];
#pragma unroll
  for (int i = 0; i < 8; ++i) acc[i] = (f32x4){0.f, 0.f, 0.f, 0.f};

#pragma unroll
  for (int c = 0; c < 4; ++c) {
    f16x8 a = *(const f16x8*)&lx[(16 * wv + m16) * XS + c * 32 + q * 8];
#pragma unroll
    for (int tt = 0; tt < 8; ++tt) {
      f16x8 b = *(const f16x8*)&lw[(tt * 16 + m16) * XS + c * 32 + q * 8];
      acc[tt] = __builtin_amdgcn_mfma_f32_16x16x32_f16(a, b, acc[tt], 0, 0, 0);
    }
  }

  // write C to this wave's own lx rows (wave-private; no barrier needed)
#pragma unroll
  for (int tt = 0; tt < 8; ++tt) {
#pragma unroll
    for (int r = 0; r < 4; ++r) {
      lx[(16 * wv + 4 * q + r) * XS + tt * 16 + m16] = (_Float16)acc[tt][r];
    }
  }

  // logits: lane -> node m16, o-part p = q (32 outputs each)
  {
    float ps = 0.f, pd = 0.f;
    int p = q;
#pragma unroll
    for (int k = 0; k < 4; ++k) {
      f16x8 hv = *(const f16x8*)&lx[(16 * wv + m16) * XS + p * 32 + k * 8];
      float4 s0 = *(const float4*)&as1[p * 32 + k * 8];
      float4 s1 = *(const float4*)&as1[p * 32 + k * 8 + 4];
      float4 d0 = *(const float4*)&ad1[p * 32 + k * 8];
      float4 d1 = *(const float4*)&ad1[p * 32 + k * 8 + 4];
      ps += (float)hv[0] * s0.x + (float)hv[1] * s0.y + (float)hv[2] * s0.z +
            (float)hv[3] * s0.w + (float)hv[4] * s1.x + (float)hv[5] * s1.y +
            (float)hv[6] * s1.z + (float)hv[7] * s1.w;
      pd += (float)hv[0] * d0.x + (float)hv[1] * d0.y + (float)hv[2] * d0.z +
            (float)hv[3] * d0.w + (float)hv[4] * d1.x + (float)hv[5] * d1.y +
            (float)hv[6] * d1.z + (float)hv[7] * d1.w;
    }
    ps += __shfl_xor(ps, 16);
    pd += __shfl_xor(pd, 16);
    int n = n0 + 16 * wv + m16;
    if (n < N && (q == 0 || q == 2)) {
      int hh = q >> 1;
      asrc1[2 * n + hh] = ps;
      adst1[2 * n + hh] = pd;
    }
  }

  // coalesced fp16 stores: 16 rows x 16 uint4 per wave -> 4 per lane
#pragma unroll
  for (int i = 0; i < 4; ++i) {
    int m = q + 4 * i;
    int n = n0 + 16 * wv + m;
    if (n < N) {
      uint4 v = *(const uint4*)&lx[(16 * wv + m) * XS + m16 * 8];
      *(uint4*)&xw1h[(size_t)n * 128 + m16 * 8] = v;
    }
  }
}

// ---------------- bucket_build: all-LDS, staged edges, ushort csr ---------

__global__ __launch_bounds__(256) void bucket_build_kernel(const unsigned* __restrict__ binned,
                                                           const int* __restrict__ bincur,
                                                           int2* __restrict__ nodeseg,
                                                           unsigned short* __restrict__ csr,
                                                           int N, int CAP) {
  __shared__ int s_deg[128];
  __shared__ int s_cur[128];
  __shared__ int s_wsum;
  __shared__ unsigned s_edges[CAPMAX];
  int b = blockIdx.x;
  int lo = b * CAP, hi = lo + bincur[b];
  int cnt = hi - lo;
  int t = threadIdx.x;
  if (t < 128) s_deg[t] = 0;
  int stg = min(cnt, CAPMAX);
  for (int i = t; i < stg; i += 256) s_edges[i] = binned[lo + i];
  __syncthreads();
  for (int i = t; i < cnt; i += 256) {
    unsigned e = (i < CAPMAX) ? s_edges[i] : binned[lo + i];
    atomicAdd(&s_deg[e >> 16], 1);
  }
  __syncthreads();
  int lane = t & 63, wv = t >> 6;
  int v = (t < 128) ? s_deg[t] : 0;
  int incl = v;
#pragma unroll
  for (int off = 1; off < 64; off <<= 1) {
    int u = __shfl_up(incl, off);
    if (lane >= off) incl += u;
  }
  if (t == 63) s_wsum = incl;  // wave-0 total
  __syncthreads();
  int excl = incl - v + ((wv == 1) ? s_wsum : 0);
  if (t < 128) {
    int node = (b << BSHIFT) + t;
    if (node < N) nodeseg[node] = make_int2(lo + excl, lo + excl + v);
    s_cur[t] = lo + excl;
  }
  __syncthreads();
  for (int i = t; i < cnt; i += 256) {
    unsigned e = (i < CAPMAX) ? s_edges[i] : binned[lo + i];
    int p = atomicAdd(&s_cur[e >> 16], 1);  // LDS atomic
    csr[p] = (unsigned short)(e & 0xFFFFu);
  }
}

// ---------------- agg1: aggregation + fused relu/bias/gemm2/logits --------

// wave per dst node. 4 rows x 16 lanes x 16B (8-edge loop, 2 loads in
// flight — measured: L2-miss BW bound; deeper MLP doesn't help).
__global__ __launch_bounds__(256) void agg1_kernel(const __half* __restrict__ xw1h,
                                                   const float* __restrict__ asrc1,
                                                   const float* __restrict__ adst1,
                                                   const float* __restrict__ b1,
                                                   const float* __restrict__ w2,
                                                   const float* __restrict__ as2,
                                                   const float* __restrict__ ad2,
                                                   const unsigned short* __restrict__ csr,
                                                   const int2* __restrict__ nodeseg,
                                                   __half* __restrict__ xw2h,
                                                   float* __restrict__ asrc2,
                                                   float* __restrict__ adst2, int N) {
  __shared__ int s_off[4][64];    // row byte offset (s * 256)
  __shared__ float2 s_w[4][64];   // exp weights per head
  int lane = threadIdx.x & 63, wv = threadIdx.x >> 6;
  int d = blockIdx.x * 4 + wv;
  if (d >= N) return;
  int c8 = lane & 15;   // channels 8*c8 .. 8*c8+7
  int row = lane >> 4;  // 0..3 edge subgroup
  int head = c8 >> 3;   // head of these channels
  int2 seg = nodeseg[d];
  int e0 = seg.x, e1 = seg.y;
  float2 asv = *(const float2*)&asrc1[2 * d];
  float2 adv = *(const float2*)&adst1[2 * d];
  float wself = __expf(lrelu(head ? (asv.y + adv.y) : (asv.x + adv.x)));

  const char* xb = (const char*)xw1h + 16 * c8;  // channel base

  float a[8];
  float sum = 0.f;
#pragma unroll
  for (int k = 0; k < 8; ++k) a[k] = 0.f;
  if (row == 0) {  // self edge handled once, by row 0
    uint4 r = *(const uint4*)(xb + ((size_t)d << 8));
    const __half2* hp = (const __half2*)&r;
#pragma unroll
    for (int k = 0; k < 4; ++k) {
      float2 v = __half22float2(hp[k]);
      a[2 * k] = wself * v.x;
      a[2 * k + 1] = wself * v.y;
    }
    sum = wself;
  }

  for (int base = e0; base < e1; base += 64) {
    int cnt = min(64, e1 - base);
    if (lane < cnt) {
      int s = (int)csr[base + lane];
      float2 aa = *(const float2*)&asrc1[2 * s];
      s_off[wv][lane] = s << 8;
      float2 w;
      w.x = __expf(lrelu(aa.x + adv.x));
      w.y = __expf(lrelu(aa.y + adv.y));
      s_w[wv][lane] = w;
    }
    // wave-private LDS: same wave wrote it; no barrier needed
    int j = 0;
    for (; j + 7 < cnt; j += 8) {
      int oA = s_off[wv][j + row];
      int oB = s_off[wv][j + 4 + row];
      float wA = ((const float*)&s_w[wv][j + row])[head];
      float wB = ((const float*)&s_w[wv][j + 4 + row])[head];
      uint4 rA = *(const uint4*)(xb + oA);
      uint4 rB = *(const uint4*)(xb + oB);
      const __half2* hA = (const __half2*)&rA;
      const __half2* hB = (const __half2*)&rB;
#pragma unroll
      for (int k = 0; k < 4; ++k) {
        float2 vA = __half22float2(hA[k]);
        float2 vB = __half22float2(hB[k]);
        a[2 * k] += wA * vA.x + wB * vB.x;
        a[2 * k + 1] += wA * vA.y + wB * vB.y;
      }
      sum += wA + wB;
    }
    for (; j < cnt; j += 4) {
      if (row < cnt - j) {
        int oA = s_off[wv][j + row];
        float wA = ((const float*)&s_w[wv][j + row])[head];
        uint4 rA = *(const uint4*)(xb + oA);
        const __half2* hA = (const __half2*)&rA;
#pragma unroll
        for (int k = 0; k < 4; ++k) {
          float2 vA = __half22float2(hA[k]);
          a[2 * k] += wA * vA.x;
          a[2 * k + 1] += wA * vA.y;
        }
        sum += wA;
      }
    }
  }

  // butterfly across the 4 rows -> every lane holds full sums for its c8
#pragma unroll
  for (int k = 0; k < 8; ++k) {
    a[k] += __shfl_xor(a[k], 16);
    a[k] += __shfl_xor(a[k], 32);
  }
  sum += __shfl_xor(sum, 16);
  sum += __shfl_xor(sum, 32);

  // h (relu'd, biased) in registers — every lane holds 8 channels
  float inv = 1.f / (sum + 1e-16f);
  float4 blo = *(const float4*)&b1[8 * c8];
  float4 bhi = *(const float4*)&b1[8 * c8 + 4];
  float h[8];
  h[0] = fmaxf(a[0] * inv + blo.x, 0.f);
  h[1] = fmaxf(a[1] * inv + blo.y, 0.f);
  h[2] = fmaxf(a[2] * inv + blo.z, 0.f);
  h[3] = fmaxf(a[3] * inv + blo.w, 0.f);
  h[4] = fmaxf(a[4] * inv + bhi.x, 0.f);
  h[5] = fmaxf(a[5] * inv + bhi.y, 0.f);
  h[6] = fmaxf(a[6] * inv + bhi.z, 0.f);
  h[7] = fmaxf(a[7] * inv + bhi.w, 0.f);

  // fused gemm2: row r computes xw2 channels r*4..r*4+3 (butterfly over 16)
  float p[4];
#pragma unroll
  for (int cc = 0; cc < 4; ++cc) {
    const float4 wlo = *(const float4*)&w2[(row * 4 + cc) * 128 + 8 * c8];
    const float4 whi = *(const float4*)&w2[(row * 4 + cc) * 128 + 8 * c8 + 4];
    p[cc] = h[0] * wlo.x + h[1] * wlo.y + h[2] * wlo.z + h[3] * wlo.w +
            h[4] * whi.x + h[5] * whi.y + h[6] * whi.z + h[7] * whi.w;
#pragma unroll
    for (int k = 1; k < 16; k <<= 1) p[cc] += __shfl_xor(p[cc], k);
  }
  float qs = 0.f, qd = 0.f;
#pragma unroll
  for (int cc = 0; cc < 4; ++cc) {
    qs += p[cc] * as2[row * 4 + cc];
    qd += p[cc] * ad2[row * 4 + cc];
  }
  qs += __shfl_xor(qs, 16);
  qs += __shfl_xor(qs, 32);
  qd += __shfl_xor(qd, 16);
  qd += __shfl_xor(qd, 32);
  if (lane == 0) {
    asrc2[d] = qs;
    adst2[d] = qd;
  }
  if (c8 == 0) {  // one lane per row stores its 4 channels (8B)
    union {
      __half hh[4];
      uint2 u;
    } pk;
#pragma unroll
    for (int cc = 0; cc < 4; ++cc) pk.hh[cc] = __float2half(p[cc]);
    *(uint2*)&xw2h[(size_t)d * 16 + row * 4] = pk.u;
  }
}

// ---------------- agg2 ----------------

// wave per dst node. 8 rows x 8 lanes x 4B; 16-edge unroll = 2 loads in
// flight. Each lane owns 2 channels (half2).
__global__ __launch_bounds__(256) void agg2_kernel(const __half* __restrict__ xw2h,
                                                   const float* __restrict__ asrc2,
                                                   const float* __restrict__ adst2,
                                                   const float* __restrict__ b2,
                                                   const unsigned short* __restrict__ csr,
                                                   const int2* __restrict__ nodeseg,
                                                   float* __restrict__ out, int N) {
  __shared__ int s_off[4][64];   // row byte offset (s * 32)
  __shared__ float s_w[4][64];
  int lane = threadIdx.x & 63, wv = threadIdx.x >> 6;
  int d = blockIdx.x * 4 + wv;
  if (d >= N) return;
  int c2 = lane & 7;   // channels 2*c2, 2*c2+1
  int row = lane >> 3; // 0..7
  int2 seg = nodeseg[d];
  int e0 = seg.x, e1 = seg.y;
  float advd = adst2[d];
  float wself = __expf(lrelu(asrc2[d] + advd));
  const char* xb = (const char*)xw2h + 4 * c2;

  float a0 = 0.f, a1 = 0.f, sum = 0.f;
  if (row == 0) {
    float2 v = __half22float2(*(const __half2*)(xb + (size_t)d * 32));
    a0 = wself * v.x;
    a1 = wself * v.y;
    sum = wself;
  }
  for (int base = e0; base < e1; base += 64) {
    int cnt = min(64, e1 - base);
    if (lane < cnt) {
      int s = (int)csr[base + lane];
      s_off[wv][lane] = s << 5;
      s_w[wv][lane] = __expf(lrelu(asrc2[s] + advd));
    }
    int j = 0;
    for (; j + 15 < cnt; j += 16) {
      int o0 = s_off[wv][j + row];
      int o1 = s_off[wv][j + 8 + row];
      float w0 = s_w[wv][j + row];
      float w1 = s_w[wv][j + 8 + row];
      float2 v0 = __half22float2(*(const __half2*)(xb + o0));
      float2 v1 = __half22float2(*(const __half2*)(xb + o1));
      a0 += w0 * v0.x + w1 * v1.x;
      a1 += w0 * v0.y + w1 * v1.y;
      sum += w0 + w1;
    }
    for (; j + 7 < cnt; j += 8) {
      int o0 = s_off[wv][j + row];
      float w0 = s_w[wv][j + row];
      float2 v0 = __half22float2(*(const __half2*)(xb + o0));
      a0 += w0 * v0.x;
      a1 += w0 * v0.y;
      sum += w0;
    }
    if (row < cnt - j) {  // tail: rows 0..cnt-j-1 take one edge each
      int o0 = s_off[wv][j + row];
      float w0 = s_w[wv][j + row];
      float2 v0 = __half22float2(*(const __half2*)(xb + o0));
      a0 += w0 * v0.x;
      a1 += w0 * v0.y;
      sum += w0;
    }
  }
#pragma unroll
  for (int k = 8; k < 64; k <<= 1) {
    a0 += __shfl_xor(a0, k);
    a1 += __shfl_xor(a1, k);
    sum += __shfl_xor(sum, k);
  }
  if (lane < 8) {
    float inv = 1.f / (sum + 1e-16f);
    float2 r;
    r.x = a0 * inv + b2[2 * c2];
    r.y = a1 * inv + b2[2 * c2 + 1];
    *(float2*)&out[(size_t)d * 16 + 2 * c2] = r;
  }
}

// ---------------------------------------------------------------------------

extern "C" void kernel_launch(void* const* d_in, const int* in_sizes, int n_in,
                              void* d_out, int out_size, void* d_ws, size_t ws_size,
                              hipStream_t stream) {
  const float* x = (const float*)d_in[0];
  const int* ei = (const int*)d_in[1];
  const float* w1 = (const float*)d_in[2];
  const float* as1 = (const float*)d_in[3];
  const float* ad1 = (const float*)d_in[4];
  const float* b1 = (const float*)d_in[5];
  const float* w2 = (const float*)d_in[6];
  const float* as2 = (const float*)d_in[7];
  const float* ad2 = (const float*)d_in[8];
  const float* b2 = (const float*)d_in[9];
  float* out = (float*)d_out;

  int N = in_sizes[0] / 128;
  int E = in_sizes[1] / 2;
  const int* srcp = ei;
  const int* dstp = ei + E;

  int B = (N + (1 << BSHIFT) - 1) >> BSHIFT;  // 391 buckets (N<=65536 req'd)
  // bucket capacity: mean + 25% slack (+512), rounded to 256 (Poisson ~16sig)
  int mean = (E + B - 1) / B;
  int CAP = (mean + mean / 4 + 512 + 255) & ~255;
  const int NB = 256;  // partition blocks
  int CH = (E + NB - 1) / NB;  // 6250 -> 25 KB LDS packing buffer
  int GB = (N + 63) / 64;  // gemm1 tiles

  char* p = (char*)d_ws;
  auto alloc = [&](size_t bytes) -> void* {
    void* r = (void*)p;
    p += (bytes + 255) & ~(size_t)255;
    return r;
  };
  __half* xw1h = (__half*)alloc((size_t)N * 128 * 2);
  float* asrc1 = (float*)alloc((size_t)N * 2 * 4);
  float* adst1 = (float*)alloc((size_t)N * 2 * 4);
  __half* xw2h = (__half*)alloc((size_t)N * 16 * 2);
  float* asrc2 = (float*)alloc((size_t)N * 4);
  float* adst2 = (float*)alloc((size_t)N * 4);
  int2* nodeseg = (int2*)alloc((size_t)N * 8);
  unsigned short* csr = (unsigned short*)alloc((size_t)B * CAP * 2);
  unsigned* binned = (unsigned*)alloc((size_t)B * CAP * 4);
  int* bincur = (int*)alloc((size_t)B * 4);

  hipMemsetAsync(bincur, 0, (size_t)B * 4, stream);
  part_gemm1_kernel<<<NB + GB, 256, 0, stream>>>(srcp, dstp, bincur, binned,
                                                 E, B, CH, CAP, NB,
                                                 x, w1, as1, ad1, xw1h, asrc1, adst1, N);
  bucket_build_kernel<<<B, 256, 0, stream>>>(binned, bincur, nodeseg, csr, N, CAP);
  agg1_kernel<<<(N + 3) / 4, 256, 0, stream>>>(xw1h, asrc1, adst1, b1, w2, as2, ad2,
                                               csr, nodeseg, xw2h, asrc2, adst2, N);
  agg2_kernel<<<(N + 3) / 4, 256, 0, stream>>>(xw2h, asrc2, adst2, b2, csr, nodeseg, out, N);
}